// Round 3
// baseline (1651.963 us; speedup 1.0000x reference)
//
#include <hip/hip_runtime.h>
#include <stdint.h>

#define NVOX 262144
#define CIN  128
#define KOFF 27

typedef short        bf16x8 __attribute__((ext_vector_type(8)));
typedef float        f32x4  __attribute__((ext_vector_type(4)));
typedef int          i32x4  __attribute__((ext_vector_type(4)));
typedef unsigned int u32x4  __attribute__((ext_vector_type(4)));

__device__ __forceinline__ unsigned short f2bf(float x) {
    unsigned int u = __builtin_bit_cast(unsigned int, x);
    u += 0x7fff + ((u >> 16) & 1);           // round-to-nearest-even
    return (unsigned short)(u >> 16);
}

// ---- detect mask dtype: int32 (all of first 256 words in {0,1}) vs byte ----
__global__ void k_detect(const int* __restrict__ mask_i32, int* __restrict__ flag) {
    bool ok = true;
    for (int i = threadIdx.x; i < 256; i += 64) {
        int v = mask_i32[i];
        ok = ok && (v == 0 || v == 1);
    }
    unsigned long long b = __ballot(ok);
    if (threadIdx.x == 0) *flag = (b == ~0ull) ? 1 : 0;
}

// ---- weight pack helper: [G,K,Nc] f32 -> MFMA B-frag bf16 ----
__device__ __forceinline__ void pack_one(const float* __restrict__ W,
                                         unsigned short* __restrict__ out,
                                         int K, int Nc, int idx) {
    int j    = idx & 7;
    int lane = (idx >> 3) & 63;
    int f    = idx >> 9;
    int ntiles = Nc >> 4, kcs = K >> 5;
    int g  = f / (kcs * ntiles);
    int rem = f - g * (kcs * ntiles);
    int kc = rem / ntiles;
    int nt = rem - kc * ntiles;
    int k  = kc * 32 + ((lane >> 4) << 3) + j;
    int n  = nt * 16 + (lane & 15);
    out[idx] = f2bf(W[((size_t)g * K + k) * Nc + n]);
}

// ---- fused prep: nbr-fold (vec4) | x->bf16 convert | all 5 weight packs ----
// block ranges: [0,6912) nbr   [6912,23296) convert   [23296,24076) packs
#define PREP_R0 6912
#define PREP_R1 23296
#define PREP_GRID 24076

__global__ __launch_bounds__(256) void k_prep(
    const int* __restrict__ nbr, const void* __restrict__ mask,
    const int* __restrict__ flag, int* __restrict__ nbr_eff,
    const float* __restrict__ x, u32x4* __restrict__ xb,
    const float* __restrict__ W00, const float* __restrict__ W10,
    const float* __restrict__ W01, const float* __restrict__ W11,
    const float* __restrict__ W12,
    unsigned short* __restrict__ w00p, unsigned short* __restrict__ w10p,
    unsigned short* __restrict__ w01p, unsigned short* __restrict__ w11p,
    unsigned short* __restrict__ w12p)
{
    int b = blockIdx.x, tid = threadIdx.x;
    if (b < PREP_R0) {
        // fold mask into neighbor list, 4 elems/thread: nbr_eff = mask ? nbr : -1
        // NT loads: nbr/mask are read exactly once -> don't pollute L3
        int base = (b * 256 + tid) * 4;
        i32x4 nv = __builtin_nontemporal_load((const i32x4*)(nbr + base));
        i32x4 r;
        if (*flag) {
            i32x4 mv = __builtin_nontemporal_load((const i32x4*)((const int*)mask + base));
            r.x = mv.x ? nv.x : -1;
            r.y = mv.y ? nv.y : -1;
            r.z = mv.z ? nv.z : -1;
            r.w = mv.w ? nv.w : -1;
        } else {
            unsigned int mv = __builtin_nontemporal_load(
                (const unsigned int*)((const unsigned char*)mask + base));
            r.x = (mv & 0x000000ffu) ? nv.x : -1;
            r.y = (mv & 0x0000ff00u) ? nv.y : -1;
            r.z = (mv & 0x00ff0000u) ? nv.z : -1;
            r.w = (mv & 0xff000000u) ? nv.w : -1;
        }
        *(i32x4*)(nbr_eff + base) = r;     // normal store: convA reads this next
    } else if (b < PREP_R1) {
        // x (f32) -> xb (bf16), 8 elems/thread; NT read of x (streamed 128 MB,
        // re-read only much later by convB; keeping it out of L3 preserves xb)
        int i = (b - PREP_R0) * 256 + tid;
        const f32x4* p = (const f32x4*)x + (size_t)i * 2;
        f32x4 a = __builtin_nontemporal_load(p);
        f32x4 c = __builtin_nontemporal_load(p + 1);
        u32x4 r;
        r.x = f2bf(a.x) | ((unsigned)f2bf(a.y) << 16);
        r.y = f2bf(a.z) | ((unsigned)f2bf(a.w) << 16);
        r.z = f2bf(c.x) | ((unsigned)f2bf(c.y) << 16);
        r.w = f2bf(c.z) | ((unsigned)f2bf(c.w) << 16);
        xb[i] = r;                         // normal store: convA gathers from it
    } else {
        // all weight packs, concatenated index space (exactly 780*256 items)
        int idx = (b - PREP_R1) * 256 + tid;
        if      (idx < 110592) pack_one(W00, w00p, 128, 32, idx);
        else if (idx < 114688) pack_one(W10, w10p, 128, 32, idx - 110592);
        else if (idx < 169984) pack_one(W01, w01p,  32, 64, idx - 114688);
        else if (idx < 197632) pack_one(W11, w11p,  32, 32, idx - 169984);
        else                   pack_one(W12, w12p,  32, 64, idx - 197632);
    }
}

// ---------------- kernel A: s = [relu(conv00(x)+b00) | relu(x@W10+b10)] -----
// 128 voxels/block, 4 waves x 32 rows (two 16-row MFMA tiles per wave).
// LDS: nbr_s (13824 B) unioned with stage (18432 B) -> 18432 B/block
// -> 8 blocks/CU co-resident (full 2048-block grid resident at once).
__global__ __launch_bounds__(256, 8) void k_convA(
    const unsigned short* __restrict__ xb,
    const int* __restrict__ nbr_eff,
    const unsigned short* __restrict__ w00, const unsigned short* __restrict__ w10,
    const float* __restrict__ b00, const float* __restrict__ b10,
    unsigned short* __restrict__ s_out)
{
    __shared__ alignas(16) unsigned char shraw[18432];
    int*            nbr_s = (int*)shraw;             // used during main loop
    unsigned short* stage = (unsigned short*)shraw;  // used after loop (union)

    int tid = threadIdx.x;
    // XCD-contiguous swizzle: round-robin dispatch % 8 -> give each XCD a
    // contiguous 1/8 voxel band so gathers hit its private L2.
    int lb = ((blockIdx.x & 7) << 8) | (blockIdx.x >> 3);   // 2048 blocks
    int vb = lb * 128;
    {   // nbr staging: vec4 + nontemporal (single use; keep L2 for gathers)
        const i32x4* nsrc = (const i32x4*)(nbr_eff + (size_t)vb * 27);
        for (int i = tid; i < 864; i += 256)
            ((i32x4*)nbr_s)[i] = __builtin_nontemporal_load(nsrc + i);
    }
    __syncthreads();

    int lane = tid & 63, wave = tid >> 6;
    int m = lane & 15, q = lane >> 4;
    int vl0 = wave * 32 + m, vl1 = vl0 + 16;

    const bf16x8 zero = {0,0,0,0,0,0,0,0};
    f32x4 zz = {0.f,0.f,0.f,0.f};
    f32x4 t00 = zz, t01 = zz, t10 = zz, t11 = zz;
    f32x4 u00 = zz, u01 = zz, u10 = zz, u11 = zz;

#pragma unroll
    for (int ko = 0; ko < 27; ++ko) {
        int j0 = nbr_s[vl0 * 27 + ko];
        int j1 = nbr_s[vl1 * 27 + ko];
        bool m0 = j0 >= 0, m1 = j1 >= 0;
        const bf16x8* xr0 = (const bf16x8*)(xb + (size_t)(m0 ? j0 : 0) * 128 + q * 8);
        const bf16x8* xr1 = (const bf16x8*)(xb + (size_t)(m1 ? j1 : 0) * 128 + q * 8);
        bf16x8 a0[4], a1[4];
#pragma unroll
        for (int kc = 0; kc < 4; ++kc) {
            a0[kc] = m0 ? xr0[kc * 4] : zero;
            a1[kc] = m1 ? xr1[kc * 4] : zero;
        }
        const bf16x8* wp = (const bf16x8*)(w00) + (size_t)ko * 8 * 64 + lane;
        __builtin_amdgcn_s_setprio(1);
#pragma unroll
        for (int kc = 0; kc < 4; ++kc) {
            bf16x8 bb0 = wp[kc * 128];
            bf16x8 bb1 = wp[kc * 128 + 64];
            t00 = __builtin_amdgcn_mfma_f32_16x16x32_bf16(a0[kc], bb0, t00, 0, 0, 0);
            t01 = __builtin_amdgcn_mfma_f32_16x16x32_bf16(a0[kc], bb1, t01, 0, 0, 0);
            t10 = __builtin_amdgcn_mfma_f32_16x16x32_bf16(a1[kc], bb0, t10, 0, 0, 0);
            t11 = __builtin_amdgcn_mfma_f32_16x16x32_bf16(a1[kc], bb1, t11, 0, 0, 0);
        }
        __builtin_amdgcn_s_setprio(0);
        if (ko == 13) {                              // center offset == own row
            const bf16x8* wq = (const bf16x8*)(w10) + lane;
            __builtin_amdgcn_s_setprio(1);
#pragma unroll
            for (int kc = 0; kc < 4; ++kc) {
                bf16x8 c0 = wq[kc * 128];
                bf16x8 c1 = wq[kc * 128 + 64];
                u00 = __builtin_amdgcn_mfma_f32_16x16x32_bf16(a0[kc], c0, u00, 0, 0, 0);
                u01 = __builtin_amdgcn_mfma_f32_16x16x32_bf16(a0[kc], c1, u01, 0, 0, 0);
                u10 = __builtin_amdgcn_mfma_f32_16x16x32_bf16(a1[kc], c0, u10, 0, 0, 0);
                u11 = __builtin_amdgcn_mfma_f32_16x16x32_bf16(a1[kc], c1, u11, 0, 0, 0);
            }
            __builtin_amdgcn_s_setprio(0);
        }
    }

    __syncthreads();   // all nbr_s reads complete before stage overwrites (union)

    // epilogue: bias + relu -> bf16 via LDS transpose, coalesced store
    int col = lane & 15;
    float bt0 = b00[col], bt1 = b00[16 + col];
    float bu0 = b10[col], bu1 = b10[16 + col];
#pragma unroll
    for (int r = 0; r < 4; ++r) {
        int row0 = wave * 32 + q * 4 + r;
        unsigned short* sp0 = stage + row0 * 72;
        sp0[col]      = f2bf(fmaxf(t00[r] + bt0, 0.f));
        sp0[16 + col] = f2bf(fmaxf(t01[r] + bt1, 0.f));
        sp0[32 + col] = f2bf(fmaxf(u00[r] + bu0, 0.f));
        sp0[48 + col] = f2bf(fmaxf(u01[r] + bu1, 0.f));
        unsigned short* sp1 = sp0 + 16 * 72;
        sp1[col]      = f2bf(fmaxf(t10[r] + bt0, 0.f));
        sp1[16 + col] = f2bf(fmaxf(t11[r] + bt1, 0.f));
        sp1[32 + col] = f2bf(fmaxf(u10[r] + bu0, 0.f));
        sp1[48 + col] = f2bf(fmaxf(u11[r] + bu1, 0.f));
    }
    __syncthreads();
    uint4* g4 = (uint4*)(s_out + (size_t)vb * 64);
    for (int i = tid; i < 1024; i += 256) {
        int row = i >> 3, c = i & 7;
        g4[row * 8 + c] = *(const uint4*)(stage + row * 72 + c * 8);
    }
}

// ---------------- kernel B: out = [conv01(t)+b01 | relu(conv11(u)+b11)@W12+b12] + x
// tl-split: the two 16-row tiles per wave are fully independent -> process
// sequentially, halving live accumulators (VGPR) to raise occupancy.
__global__ __launch_bounds__(256, 6) void k_convB(
    const unsigned short* __restrict__ s_in,
    const float* __restrict__ x,
    const int* __restrict__ nbr_eff,
    const unsigned short* __restrict__ w01, const unsigned short* __restrict__ w11,
    const unsigned short* __restrict__ w12,
    const float* __restrict__ b01, const float* __restrict__ b11,
    const float* __restrict__ b12,
    float* __restrict__ out)
{
    __shared__ alignas(16) int nbr_s[128 * 27];
    __shared__ unsigned short vstage[4][16 * 40];   // wave-private, reused per tl

    int tid = threadIdx.x;
    int lb = ((blockIdx.x & 7) << 8) | (blockIdx.x >> 3);
    int vb = lb * 128;
    {
        const i32x4* nsrc = (const i32x4*)(nbr_eff + (size_t)vb * 27);
        for (int i = tid; i < 864; i += 256)
            ((i32x4*)nbr_s)[i] = __builtin_nontemporal_load(nsrc + i);
    }
    __syncthreads();

    int lane = tid & 63, wave = tid >> 6;
    int m = lane & 15, q = lane >> 4;
    int col = m;

    const bf16x8 zero = {0,0,0,0,0,0,0,0};
    f32x4 zz = {0.f,0.f,0.f,0.f};

    float bv0 = b11[col], bv1 = b11[16 + col];
    float bo[4], bp[4];
#pragma unroll
    for (int nt = 0; nt < 4; ++nt) { bo[nt] = b01[nt * 16 + col]; bp[nt] = b12[nt * 16 + col]; }
    const bf16x8* wp3 = (const bf16x8*)(w12) + lane;

#pragma unroll 1
    for (int tl = 0; tl < 2; ++tl) {
        int vl = wave * 32 + tl * 16 + m;
        f32x4 o0 = zz, o1 = zz, o2 = zz, o3 = zz;
        f32x4 v0 = zz, v1 = zz;

#pragma unroll
        for (int ko = 0; ko < 27; ++ko) {
            int j = nbr_s[vl * 27 + ko];
            bool mk = j >= 0;
            const bf16x8* sr = (const bf16x8*)(s_in + (size_t)(mk ? j : 0) * 64 + q * 8);
            bf16x8 at = mk ? sr[0] : zero;
            bf16x8 au = mk ? sr[4] : zero;
            const bf16x8* wp1 = (const bf16x8*)(w01) + (size_t)ko * 4 * 64 + lane;
            const bf16x8* wp2 = (const bf16x8*)(w11) + (size_t)ko * 2 * 64 + lane;
            __builtin_amdgcn_s_setprio(1);
            o0 = __builtin_amdgcn_mfma_f32_16x16x32_bf16(at, wp1[0],   o0, 0, 0, 0);
            o1 = __builtin_amdgcn_mfma_f32_16x16x32_bf16(at, wp1[64],  o1, 0, 0, 0);
            o2 = __builtin_amdgcn_mfma_f32_16x16x32_bf16(at, wp1[128], o2, 0, 0, 0);
            o3 = __builtin_amdgcn_mfma_f32_16x16x32_bf16(at, wp1[192], o3, 0, 0, 0);
            v0 = __builtin_amdgcn_mfma_f32_16x16x32_bf16(au, wp2[0],   v0, 0, 0, 0);
            v1 = __builtin_amdgcn_mfma_f32_16x16x32_bf16(au, wp2[64],  v1, 0, 0, 0);
            __builtin_amdgcn_s_setprio(0);
        }

        // v = relu(v + b11): C-layout -> A-layout via wave-private LDS round-trip
        unsigned short* vs = vstage[wave];
#pragma unroll
        for (int r = 0; r < 4; ++r) {
            int row = q * 4 + r;
            vs[row * 40 + col]      = f2bf(fmaxf(v0[r] + bv0, 0.f));
            vs[row * 40 + 16 + col] = f2bf(fmaxf(v1[r] + bv1, 0.f));
        }
        bf16x8 av = *(const bf16x8*)(vs + m * 40 + q * 8);
        f32x4 p0 = __builtin_amdgcn_mfma_f32_16x16x32_bf16(av, wp3[0],   zz, 0, 0, 0);
        f32x4 p1 = __builtin_amdgcn_mfma_f32_16x16x32_bf16(av, wp3[64],  zz, 0, 0, 0);
        f32x4 p2 = __builtin_amdgcn_mfma_f32_16x16x32_bf16(av, wp3[128], zz, 0, 0, 0);
        f32x4 p3 = __builtin_amdgcn_mfma_f32_16x16x32_bf16(av, wp3[192], zz, 0, 0, 0);

        // direct C-layout stores: 16-lane 64B segments, residual add from x
        // x / out are streamed exactly once -> nontemporal, keep L2 for gathers
        f32x4 oo[4] = {o0, o1, o2, o3};
        f32x4 pp[4] = {p0, p1, p2, p3};
#pragma unroll
        for (int r = 0; r < 4; ++r) {
            int row = vb + wave * 32 + tl * 16 + q * 4 + r;
            const float* xr = x + (size_t)row * 128;
            float* orow = out + (size_t)row * 128;
#pragma unroll
            for (int nt = 0; nt < 4; ++nt) {
                float x0 = __builtin_nontemporal_load(xr + nt * 16 + col);
                float x1 = __builtin_nontemporal_load(xr + 64 + nt * 16 + col);
                __builtin_nontemporal_store(oo[nt][r] + bo[nt] + x0,
                                            orow + nt * 16 + col);
                __builtin_nontemporal_store(pp[nt][r] + bp[nt] + x1,
                                            orow + 64 + nt * 16 + col);
            }
        }
    }
}

extern "C" void kernel_launch(void* const* d_in, const int* in_sizes, int n_in,
                              void* d_out, int out_size, void* d_ws, size_t ws_size,
                              hipStream_t stream) {
    const float* x   = (const float*)d_in[0];
    const int*   nbr = (const int*)d_in[1];
    const void*  mask = d_in[2];
    const float* W00 = (const float*)d_in[3];
    const float* b00 = (const float*)d_in[4];
    const float* W01 = (const float*)d_in[5];
    const float* b01 = (const float*)d_in[6];
    const float* W10 = (const float*)d_in[7];
    const float* b10 = (const float*)d_in[8];
    const float* W11 = (const float*)d_in[9];
    const float* b11 = (const float*)d_in[10];
    const float* W12 = (const float*)d_in[11];
    const float* b12 = (const float*)d_in[12];
    float* out = (float*)d_out;

    char* ws = (char*)d_ws;
    unsigned short* xb     = (unsigned short*)(ws);               // 64 MB
    unsigned short* s      = (unsigned short*)(ws + 67108864);    // 32 MB
    int*            nbr_eff= (int*)           (ws + 100663296);   // 27 MB
    unsigned short* w00p   = (unsigned short*)(ws + 128974848);   // 216 KB
    unsigned short* w10p   = (unsigned short*)(ws + 129196032);   // 8 KB
    unsigned short* w01p   = (unsigned short*)(ws + 129204224);   // 108 KB
    unsigned short* w11p   = (unsigned short*)(ws + 129314816);   // 54 KB
    unsigned short* w12p   = (unsigned short*)(ws + 129370112);   // 4 KB
    int*            flag   = (int*)           (ws + 129374208);

    k_detect<<<1, 64, 0, stream>>>((const int*)mask, flag);
    k_prep<<<PREP_GRID, 256, 0, stream>>>(nbr, mask, flag, nbr_eff, x, (u32x4*)xb,
                                          W00, W10, W01, W11, W12,
                                          w00p, w10p, w01p, w11p, w12p);
    k_convA<<<NVOX/128, 256, 0, stream>>>(xb, nbr_eff, w00p, w10p, b00, b10, s);
    k_convB<<<NVOX/128, 256, 0, stream>>>(s, x, nbr_eff, w01p, w11p, w12p,
                                          b01, b11, b12, out);
}

// Round 4
// 649.581 us; speedup vs baseline: 2.5431x; 2.5431x over previous
//
#include <hip/hip_runtime.h>
#include <stdint.h>

#define NVOX 262144
#define CIN  128
#define KOFF 27

typedef short        bf16x8 __attribute__((ext_vector_type(8)));
typedef float        f32x4  __attribute__((ext_vector_type(4)));
typedef int          i32x4  __attribute__((ext_vector_type(4)));
typedef unsigned int u32x4  __attribute__((ext_vector_type(4)));

__device__ __forceinline__ unsigned short f2bf(float x) {
    unsigned int u = __builtin_bit_cast(unsigned int, x);
    u += 0x7fff + ((u >> 16) & 1);           // round-to-nearest-even
    return (unsigned short)(u >> 16);
}

// ---- detect mask dtype: int32 (all of first 256 words in {0,1}) vs byte ----
__global__ void k_detect(const int* __restrict__ mask_i32, int* __restrict__ flag) {
    bool ok = true;
    for (int i = threadIdx.x; i < 256; i += 64) {
        int v = mask_i32[i];
        ok = ok && (v == 0 || v == 1);
    }
    unsigned long long b = __ballot(ok);
    if (threadIdx.x == 0) *flag = (b == ~0ull) ? 1 : 0;
}

// ---- weight pack helper: [G,K,Nc] f32 -> MFMA B-frag bf16 ----
__device__ __forceinline__ void pack_one(const float* __restrict__ W,
                                         unsigned short* __restrict__ out,
                                         int K, int Nc, int idx) {
    int j    = idx & 7;
    int lane = (idx >> 3) & 63;
    int f    = idx >> 9;
    int ntiles = Nc >> 4, kcs = K >> 5;
    int g  = f / (kcs * ntiles);
    int rem = f - g * (kcs * ntiles);
    int kc = rem / ntiles;
    int nt = rem - kc * ntiles;
    int k  = kc * 32 + ((lane >> 4) << 3) + j;
    int n  = nt * 16 + (lane & 15);
    out[idx] = f2bf(W[((size_t)g * K + k) * Nc + n]);
}

// ---- fused prep: nbr-fold (vec4) | x->bf16 convert | all 5 weight packs ----
// block ranges: [0,6912) nbr   [6912,23296) convert   [23296,24076) packs
#define PREP_R0 6912
#define PREP_R1 23296
#define PREP_GRID 24076

__global__ __launch_bounds__(256) void k_prep(
    const int* __restrict__ nbr, const void* __restrict__ mask,
    const int* __restrict__ flag, int* __restrict__ nbr_eff,
    const float* __restrict__ x, u32x4* __restrict__ xb,
    const float* __restrict__ W00, const float* __restrict__ W10,
    const float* __restrict__ W01, const float* __restrict__ W11,
    const float* __restrict__ W12,
    unsigned short* __restrict__ w00p, unsigned short* __restrict__ w10p,
    unsigned short* __restrict__ w01p, unsigned short* __restrict__ w11p,
    unsigned short* __restrict__ w12p)
{
    int b = blockIdx.x, tid = threadIdx.x;
    if (b < PREP_R0) {
        // fold mask into neighbor list, 4 elems/thread: nbr_eff = mask ? nbr : -1
        int base = (b * 256 + tid) * 4;
        i32x4 nv = *(const i32x4*)(nbr + base);
        i32x4 r;
        if (*flag) {
            i32x4 mv = *(const i32x4*)((const int*)mask + base);
            r.x = mv.x ? nv.x : -1;
            r.y = mv.y ? nv.y : -1;
            r.z = mv.z ? nv.z : -1;
            r.w = mv.w ? nv.w : -1;
        } else {
            uchar4 mv = *(const uchar4*)((const unsigned char*)mask + base);
            r.x = mv.x ? nv.x : -1;
            r.y = mv.y ? nv.y : -1;
            r.z = mv.z ? nv.z : -1;
            r.w = mv.w ? nv.w : -1;
        }
        *(i32x4*)(nbr_eff + base) = r;
    } else if (b < PREP_R1) {
        // x (f32) -> xb (bf16), 8 elems/thread
        int i = (b - PREP_R0) * 256 + tid;
        const float4* p = (const float4*)x + (size_t)i * 2;
        float4 a = p[0], c = p[1];
        uint4 r;
        r.x = f2bf(a.x) | ((unsigned)f2bf(a.y) << 16);
        r.y = f2bf(a.z) | ((unsigned)f2bf(a.w) << 16);
        r.z = f2bf(c.x) | ((unsigned)f2bf(c.y) << 16);
        r.w = f2bf(c.z) | ((unsigned)f2bf(c.w) << 16);
        ((uint4*)xb)[i] = r;
    } else {
        // all weight packs, concatenated index space (exactly 780*256 items)
        int idx = (b - PREP_R1) * 256 + tid;
        if      (idx < 110592) pack_one(W00, w00p, 128, 32, idx);
        else if (idx < 114688) pack_one(W10, w10p, 128, 32, idx - 110592);
        else if (idx < 169984) pack_one(W01, w01p,  32, 64, idx - 114688);
        else if (idx < 197632) pack_one(W11, w11p,  32, 32, idx - 169984);
        else                   pack_one(W12, w12p,  32, 64, idx - 197632);
    }
}

// ---------------- kernel A: s = [relu(conv00(x)+b00) | relu(x@W10+b10)] -----
// 128 voxels/block, 4 waves x 32 rows (two 16-row MFMA tiles per wave).
// LDS: nbr_s (13824 B) UNIONED with stage (18432 B) -> 18432 B/block
// -> 8 blocks/CU (LDS-limited; VGPR 52 naturally -> not limiting).
// NOTE: no min-waves launch_bounds clamp — R3 showed (256,N) clamps force
// accumulator spill-to-scratch (VGPR 108->40, WRITE 12x, 5x slowdown).
__global__ __launch_bounds__(256) void k_convA(
    const unsigned short* __restrict__ xb,
    const int* __restrict__ nbr_eff,
    const unsigned short* __restrict__ w00, const unsigned short* __restrict__ w10,
    const float* __restrict__ b00, const float* __restrict__ b10,
    unsigned short* __restrict__ s_out)
{
    __shared__ alignas(16) unsigned char shraw[18432];
    int*            nbr_s = (int*)shraw;             // live during main loop
    unsigned short* stage = (unsigned short*)shraw;  // live after loop (union)

    int tid = threadIdx.x;
    // XCD-contiguous swizzle: round-robin dispatch % 8 -> give each XCD a
    // contiguous 1/8 voxel band so gathers hit its private L2.
    int lb = ((blockIdx.x & 7) << 8) | (blockIdx.x >> 3);   // 2048 blocks
    int vb = lb * 128;
    {   // nbr staging: vec4 + nontemporal (single use; keep L2 for gathers)
        const i32x4* nsrc = (const i32x4*)(nbr_eff + (size_t)vb * 27);
        for (int i = tid; i < 864; i += 256)
            ((i32x4*)nbr_s)[i] = __builtin_nontemporal_load(nsrc + i);
    }
    __syncthreads();

    int lane = tid & 63, wave = tid >> 6;
    int m = lane & 15, q = lane >> 4;
    int vl0 = wave * 32 + m, vl1 = vl0 + 16;

    const bf16x8 zero = {0,0,0,0,0,0,0,0};
    f32x4 zz = {0.f,0.f,0.f,0.f};
    f32x4 t00 = zz, t01 = zz, t10 = zz, t11 = zz;
    f32x4 u00 = zz, u01 = zz, u10 = zz, u11 = zz;

#pragma unroll
    for (int ko = 0; ko < 27; ++ko) {
        int j0 = nbr_s[vl0 * 27 + ko];
        int j1 = nbr_s[vl1 * 27 + ko];
        bool m0 = j0 >= 0, m1 = j1 >= 0;
        const bf16x8* xr0 = (const bf16x8*)(xb + (size_t)(m0 ? j0 : 0) * 128 + q * 8);
        const bf16x8* xr1 = (const bf16x8*)(xb + (size_t)(m1 ? j1 : 0) * 128 + q * 8);
        bf16x8 a0[4], a1[4];
#pragma unroll
        for (int kc = 0; kc < 4; ++kc) {
            a0[kc] = m0 ? xr0[kc * 4] : zero;
            a1[kc] = m1 ? xr1[kc * 4] : zero;
        }
        const bf16x8* wp = (const bf16x8*)(w00) + (size_t)ko * 8 * 64 + lane;
        __builtin_amdgcn_s_setprio(1);
#pragma unroll
        for (int kc = 0; kc < 4; ++kc) {
            bf16x8 bb0 = wp[kc * 128];
            bf16x8 bb1 = wp[kc * 128 + 64];
            t00 = __builtin_amdgcn_mfma_f32_16x16x32_bf16(a0[kc], bb0, t00, 0, 0, 0);
            t01 = __builtin_amdgcn_mfma_f32_16x16x32_bf16(a0[kc], bb1, t01, 0, 0, 0);
            t10 = __builtin_amdgcn_mfma_f32_16x16x32_bf16(a1[kc], bb0, t10, 0, 0, 0);
            t11 = __builtin_amdgcn_mfma_f32_16x16x32_bf16(a1[kc], bb1, t11, 0, 0, 0);
        }
        __builtin_amdgcn_s_setprio(0);
        if (ko == 13) {                              // center offset == own row
            const bf16x8* wq = (const bf16x8*)(w10) + lane;
            __builtin_amdgcn_s_setprio(1);
#pragma unroll
            for (int kc = 0; kc < 4; ++kc) {
                bf16x8 c0 = wq[kc * 128];
                bf16x8 c1 = wq[kc * 128 + 64];
                u00 = __builtin_amdgcn_mfma_f32_16x16x32_bf16(a0[kc], c0, u00, 0, 0, 0);
                u01 = __builtin_amdgcn_mfma_f32_16x16x32_bf16(a0[kc], c1, u01, 0, 0, 0);
                u10 = __builtin_amdgcn_mfma_f32_16x16x32_bf16(a1[kc], c0, u10, 0, 0, 0);
                u11 = __builtin_amdgcn_mfma_f32_16x16x32_bf16(a1[kc], c1, u11, 0, 0, 0);
            }
            __builtin_amdgcn_s_setprio(0);
        }
    }

    __syncthreads();   // all nbr_s reads done before stage overwrites (union)

    // epilogue: bias + relu -> bf16 via LDS transpose, coalesced store
    int col = lane & 15;
    float bt0 = b00[col], bt1 = b00[16 + col];
    float bu0 = b10[col], bu1 = b10[16 + col];
#pragma unroll
    for (int r = 0; r < 4; ++r) {
        int row0 = wave * 32 + q * 4 + r;
        unsigned short* sp0 = stage + row0 * 72;
        sp0[col]      = f2bf(fmaxf(t00[r] + bt0, 0.f));
        sp0[16 + col] = f2bf(fmaxf(t01[r] + bt1, 0.f));
        sp0[32 + col] = f2bf(fmaxf(u00[r] + bu0, 0.f));
        sp0[48 + col] = f2bf(fmaxf(u01[r] + bu1, 0.f));
        unsigned short* sp1 = sp0 + 16 * 72;
        sp1[col]      = f2bf(fmaxf(t10[r] + bt0, 0.f));
        sp1[16 + col] = f2bf(fmaxf(t11[r] + bt1, 0.f));
        sp1[32 + col] = f2bf(fmaxf(u10[r] + bu0, 0.f));
        sp1[48 + col] = f2bf(fmaxf(u11[r] + bu1, 0.f));
    }
    __syncthreads();
    uint4* g4 = (uint4*)(s_out + (size_t)vb * 64);
    for (int i = tid; i < 1024; i += 256) {
        int row = i >> 3, c = i & 7;
        g4[row * 8 + c] = *(const uint4*)(stage + row * 72 + c * 8);
    }
}

// ---------------- kernel B: out = [conv01(t)+b01 | relu(conv11(u)+b11)@W12+b12] + x
// (exact R2 structure: joint tiles, no min-waves clamp — measured 231 us)
__global__ __launch_bounds__(256) void k_convB(
    const unsigned short* __restrict__ s_in,
    const float* __restrict__ x,
    const int* __restrict__ nbr_eff,
    const unsigned short* __restrict__ w01, const unsigned short* __restrict__ w11,
    const unsigned short* __restrict__ w12,
    const float* __restrict__ b01, const float* __restrict__ b11,
    const float* __restrict__ b12,
    float* __restrict__ out)
{
    __shared__ alignas(16) int nbr_s[128 * 27];
    __shared__ unsigned short vstage[4][2][16 * 40];

    int tid = threadIdx.x;
    int lb = ((blockIdx.x & 7) << 8) | (blockIdx.x >> 3);
    int vb = lb * 128;
    {
        const i32x4* nsrc = (const i32x4*)(nbr_eff + (size_t)vb * 27);
        for (int i = tid; i < 864; i += 256)
            ((i32x4*)nbr_s)[i] = __builtin_nontemporal_load(nsrc + i);
    }
    __syncthreads();

    int lane = tid & 63, wave = tid >> 6;
    int m = lane & 15, q = lane >> 4;
    int vl0 = wave * 32 + m, vl1 = vl0 + 16;

    const bf16x8 zero = {0,0,0,0,0,0,0,0};
    f32x4 zz = {0.f,0.f,0.f,0.f};
    f32x4 o[2][4];
    f32x4 v[2][2];
#pragma unroll
    for (int tl = 0; tl < 2; ++tl) {
        o[tl][0] = zz; o[tl][1] = zz; o[tl][2] = zz; o[tl][3] = zz;
        v[tl][0] = zz; v[tl][1] = zz;
    }

#pragma unroll
    for (int ko = 0; ko < 27; ++ko) {
        int j0 = nbr_s[vl0 * 27 + ko];
        int j1 = nbr_s[vl1 * 27 + ko];
        bool m0 = j0 >= 0, m1 = j1 >= 0;
        const bf16x8* sr0 = (const bf16x8*)(s_in + (size_t)(m0 ? j0 : 0) * 64 + q * 8);
        const bf16x8* sr1 = (const bf16x8*)(s_in + (size_t)(m1 ? j1 : 0) * 64 + q * 8);
        bf16x8 at0 = m0 ? sr0[0] : zero;
        bf16x8 au0 = m0 ? sr0[4] : zero;
        bf16x8 at1 = m1 ? sr1[0] : zero;
        bf16x8 au1 = m1 ? sr1[4] : zero;
        const bf16x8* wp1 = (const bf16x8*)(w01) + (size_t)ko * 4 * 64 + lane;
        __builtin_amdgcn_s_setprio(1);
#pragma unroll
        for (int nt = 0; nt < 4; ++nt) {
            bf16x8 bb = wp1[nt * 64];
            o[0][nt] = __builtin_amdgcn_mfma_f32_16x16x32_bf16(at0, bb, o[0][nt], 0, 0, 0);
            o[1][nt] = __builtin_amdgcn_mfma_f32_16x16x32_bf16(at1, bb, o[1][nt], 0, 0, 0);
        }
        const bf16x8* wp2 = (const bf16x8*)(w11) + (size_t)ko * 2 * 64 + lane;
#pragma unroll
        for (int nt = 0; nt < 2; ++nt) {
            bf16x8 bb = wp2[nt * 64];
            v[0][nt] = __builtin_amdgcn_mfma_f32_16x16x32_bf16(au0, bb, v[0][nt], 0, 0, 0);
            v[1][nt] = __builtin_amdgcn_mfma_f32_16x16x32_bf16(au1, bb, v[1][nt], 0, 0, 0);
        }
        __builtin_amdgcn_s_setprio(0);
    }

    // v = relu(v + b11): C-layout -> A-layout via LDS round-trip
    int col = lane & 15;
    {
        float bv0 = b11[col], bv1 = b11[16 + col];
#pragma unroll
        for (int tl = 0; tl < 2; ++tl) {
            unsigned short* vs = vstage[wave][tl];
#pragma unroll
            for (int r = 0; r < 4; ++r) {
                int row = q * 4 + r;
                vs[row * 40 + col]      = f2bf(fmaxf(v[tl][0][r] + bv0, 0.f));
                vs[row * 40 + 16 + col] = f2bf(fmaxf(v[tl][1][r] + bv1, 0.f));
            }
        }
    }
    __syncthreads();
    const bf16x8* wp3 = (const bf16x8*)(w12) + lane;
    bf16x8 w3[4];
#pragma unroll
    for (int nt = 0; nt < 4; ++nt) w3[nt] = wp3[nt * 64];
    f32x4 p[2][4];
#pragma unroll
    for (int tl = 0; tl < 2; ++tl) {
        bf16x8 av = *(const bf16x8*)(vstage[wave][tl] + m * 40 + q * 8);
#pragma unroll
        for (int nt = 0; nt < 4; ++nt)
            p[tl][nt] = __builtin_amdgcn_mfma_f32_16x16x32_bf16(av, w3[nt], zz, 0, 0, 0);
    }

    // direct C-layout stores: 16-lane 64B segments, residual add from x
    // x / out are streamed exactly once -> nontemporal, keep L2 for s gathers
    float bo[4], bp[4];
#pragma unroll
    for (int nt = 0; nt < 4; ++nt) { bo[nt] = b01[nt * 16 + col]; bp[nt] = b12[nt * 16 + col]; }
#pragma unroll
    for (int tl = 0; tl < 2; ++tl) {
#pragma unroll
        for (int r = 0; r < 4; ++r) {
            int row = vb + wave * 32 + tl * 16 + q * 4 + r;
            const float* xr = x + (size_t)row * 128;
            float* orow = out + (size_t)row * 128;
#pragma unroll
            for (int nt = 0; nt < 4; ++nt) {
                float x0 = __builtin_nontemporal_load(xr + nt * 16 + col);
                float x1 = __builtin_nontemporal_load(xr + 64 + nt * 16 + col);
                __builtin_nontemporal_store(o[tl][nt][r] + bo[nt] + x0,
                                            orow + nt * 16 + col);
                __builtin_nontemporal_store(p[tl][nt][r] + bp[nt] + x1,
                                            orow + 64 + nt * 16 + col);
            }
        }
    }
}

extern "C" void kernel_launch(void* const* d_in, const int* in_sizes, int n_in,
                              void* d_out, int out_size, void* d_ws, size_t ws_size,
                              hipStream_t stream) {
    const float* x   = (const float*)d_in[0];
    const int*   nbr = (const int*)d_in[1];
    const void*  mask = d_in[2];
    const float* W00 = (const float*)d_in[3];
    const float* b00 = (const float*)d_in[4];
    const float* W01 = (const float*)d_in[5];
    const float* b01 = (const float*)d_in[6];
    const float* W10 = (const float*)d_in[7];
    const float* b10 = (const float*)d_in[8];
    const float* W11 = (const float*)d_in[9];
    const float* b11 = (const float*)d_in[10];
    const float* W12 = (const float*)d_in[11];
    const float* b12 = (const float*)d_in[12];
    float* out = (float*)d_out;

    char* ws = (char*)d_ws;
    unsigned short* xb     = (unsigned short*)(ws);               // 64 MB
    unsigned short* s      = (unsigned short*)(ws + 67108864);    // 32 MB
    int*            nbr_eff= (int*)           (ws + 100663296);   // 27 MB
    unsigned short* w00p   = (unsigned short*)(ws + 128974848);   // 216 KB
    unsigned short* w10p   = (unsigned short*)(ws + 129196032);   // 8 KB
    unsigned short* w01p   = (unsigned short*)(ws + 129204224);   // 108 KB
    unsigned short* w11p   = (unsigned short*)(ws + 129314816);   // 54 KB
    unsigned short* w12p   = (unsigned short*)(ws + 129370112);   // 4 KB
    int*            flag   = (int*)           (ws + 129374208);

    k_detect<<<1, 64, 0, stream>>>((const int*)mask, flag);
    k_prep<<<PREP_GRID, 256, 0, stream>>>(nbr, mask, flag, nbr_eff, x, (u32x4*)xb,
                                          W00, W10, W01, W11, W12,
                                          w00p, w10p, w01p, w11p, w12p);
    k_convA<<<NVOX/128, 256, 0, stream>>>(xb, nbr_eff, w00p, w10p, b00, b10, s);
    k_convB<<<NVOX/128, 256, 0, stream>>>(s, x, nbr_eff, w01p, w11p, w12p,
                                          b01, b11, b12, out);
}

// Round 6
// 578.865 us; speedup vs baseline: 2.8538x; 1.1222x over previous
//
#include <hip/hip_runtime.h>
#include <stdint.h>

#define NVOX 262144
#define CIN  128
#define KOFF 27

typedef short        bf16x8 __attribute__((ext_vector_type(8)));
typedef float        f32x4  __attribute__((ext_vector_type(4)));
typedef int          i32x4  __attribute__((ext_vector_type(4)));
typedef unsigned int u32x4  __attribute__((ext_vector_type(4)));

__device__ __forceinline__ unsigned short f2bf(float x) {
    unsigned int u = __builtin_bit_cast(unsigned int, x);
    u += 0x7fff + ((u >> 16) & 1);           // round-to-nearest-even
    return (unsigned short)(u >> 16);
}

// ---- detect mask dtype: int32 (all of first 256 words in {0,1}) vs byte ----
__global__ void k_detect(const int* __restrict__ mask_i32, int* __restrict__ flag) {
    bool ok = true;
    for (int i = threadIdx.x; i < 256; i += 64) {
        int v = mask_i32[i];
        ok = ok && (v == 0 || v == 1);
    }
    unsigned long long b = __ballot(ok);
    if (threadIdx.x == 0) *flag = (b == ~0ull) ? 1 : 0;
}

// ---- weight pack helper: [G,K,Nc] f32 -> MFMA B-frag bf16 ----
__device__ __forceinline__ void pack_one(const float* __restrict__ W,
                                         unsigned short* __restrict__ out,
                                         int K, int Nc, int idx) {
    int j    = idx & 7;
    int lane = (idx >> 3) & 63;
    int f    = idx >> 9;
    int ntiles = Nc >> 4, kcs = K >> 5;
    int g  = f / (kcs * ntiles);
    int rem = f - g * (kcs * ntiles);
    int kc = rem / ntiles;
    int nt = rem - kc * ntiles;
    int k  = kc * 32 + ((lane >> 4) << 3) + j;
    int n  = nt * 16 + (lane & 15);
    out[idx] = f2bf(W[((size_t)g * K + k) * Nc + n]);
}

// ---- fused prep: nbr-fold (vec4) | x->bf16 convert | all 5 weight packs ----
// block ranges: [0,6912) nbr   [6912,23296) convert   [23296,24076) packs
#define PREP_R0 6912
#define PREP_R1 23296
#define PREP_GRID 24076

__global__ __launch_bounds__(256) void k_prep(
    const int* __restrict__ nbr, const void* __restrict__ mask,
    const int* __restrict__ flag, int* __restrict__ nbr_eff,
    const float* __restrict__ x, u32x4* __restrict__ xb,
    const float* __restrict__ W00, const float* __restrict__ W10,
    const float* __restrict__ W01, const float* __restrict__ W11,
    const float* __restrict__ W12,
    unsigned short* __restrict__ w00p, unsigned short* __restrict__ w10p,
    unsigned short* __restrict__ w01p, unsigned short* __restrict__ w11p,
    unsigned short* __restrict__ w12p)
{
    int b = blockIdx.x, tid = threadIdx.x;
    if (b < PREP_R0) {
        // fold mask into neighbor list, 4 elems/thread: nbr_eff = mask ? nbr : -1
        int base = (b * 256 + tid) * 4;
        i32x4 nv = *(const i32x4*)(nbr + base);
        i32x4 r;
        if (*flag) {
            i32x4 mv = *(const i32x4*)((const int*)mask + base);
            r.x = mv.x ? nv.x : -1;
            r.y = mv.y ? nv.y : -1;
            r.z = mv.z ? nv.z : -1;
            r.w = mv.w ? nv.w : -1;
        } else {
            uchar4 mv = *(const uchar4*)((const unsigned char*)mask + base);
            r.x = mv.x ? nv.x : -1;
            r.y = mv.y ? nv.y : -1;
            r.z = mv.z ? nv.z : -1;
            r.w = mv.w ? nv.w : -1;
        }
        *(i32x4*)(nbr_eff + base) = r;
    } else if (b < PREP_R1) {
        // x (f32) -> xb (bf16), 8 elems/thread
        int i = (b - PREP_R0) * 256 + tid;
        const float4* p = (const float4*)x + (size_t)i * 2;
        float4 a = p[0], c = p[1];
        uint4 r;
        r.x = f2bf(a.x) | ((unsigned)f2bf(a.y) << 16);
        r.y = f2bf(a.z) | ((unsigned)f2bf(a.w) << 16);
        r.z = f2bf(c.x) | ((unsigned)f2bf(c.y) << 16);
        r.w = f2bf(c.z) | ((unsigned)f2bf(c.w) << 16);
        ((uint4*)xb)[i] = r;
    } else {
        // all weight packs, concatenated index space (exactly 780*256 items)
        int idx = (b - PREP_R1) * 256 + tid;
        if      (idx < 110592) pack_one(W00, w00p, 128, 32, idx);
        else if (idx < 114688) pack_one(W10, w10p, 128, 32, idx - 110592);
        else if (idx < 169984) pack_one(W01, w01p,  32, 64, idx - 114688);
        else if (idx < 197632) pack_one(W11, w11p,  32, 32, idx - 169984);
        else                   pack_one(W12, w12p,  32, 64, idx - 197632);
    }
}

// ---------------- kernel A: s = [relu(conv00(x)+b00) | relu(x@W10+b10)] -----
// 128 voxels/block, 4 waves x 32 rows (two 16-row MFMA tiles per wave).
// Weight slices (8 KB/ko) staged in LDS once per block (reg-staged,
// double-buffered, 1 barrier/ko): dedups the 4x per-wave weight read that
// made the kernel TCP-line-throughput bound (R4 diagnosis).
// LDS: nbr_s[13824] + wbuf[2][8192] = 30208 B; epilogue stage unions at 0.
__global__ __launch_bounds__(256) void k_convA(
    const unsigned short* __restrict__ xb,
    const int* __restrict__ nbr_eff,
    const unsigned short* __restrict__ w00, const unsigned short* __restrict__ w10,
    const float* __restrict__ b00, const float* __restrict__ b10,
    unsigned short* __restrict__ s_out)
{
    __shared__ alignas(16) unsigned char shraw[30208];
    int*            nbr_s = (int*)shraw;                          // [0,13824)
    unsigned short* wbuf  = (unsigned short*)(shraw + 13824);     // 2 x 4096 us
    unsigned short* stage = (unsigned short*)shraw;               // post-loop union

    int tid = threadIdx.x;
    // XCD-contiguous swizzle
    int lb = ((blockIdx.x & 7) << 8) | (blockIdx.x >> 3);   // 2048 blocks
    int vb = lb * 128;
    {   // nbr staging: vec4 + nontemporal (single use)
        const i32x4* nsrc = (const i32x4*)(nbr_eff + (size_t)vb * 27);
        for (int i = tid; i < 864; i += 256)
            ((i32x4*)nbr_s)[i] = __builtin_nontemporal_load(nsrc + i);
    }
    {   // stage ko=0 weight slice (8192 B, 2 x uint4 per thread)
        const uint4* g = (const uint4*)w00;
        uint4 p0 = g[tid], p1 = g[tid + 256];
        ((uint4*)wbuf)[tid] = p0;
        ((uint4*)wbuf)[tid + 256] = p1;
    }
    __syncthreads();   // nbr_s + wbuf[0] ready

    int lane = tid & 63, wave = tid >> 6;
    int m = lane & 15, q = lane >> 4;
    int vl0 = wave * 32 + m, vl1 = vl0 + 16;

    const bf16x8 zero = {0,0,0,0,0,0,0,0};
    f32x4 zz = {0.f,0.f,0.f,0.f};
    f32x4 t00 = zz, t01 = zz, t10 = zz, t11 = zz;
    f32x4 u00 = zz, u01 = zz, u10 = zz, u11 = zz;

#pragma unroll
    for (int ko = 0; ko < 27; ++ko) {
        const unsigned short* cur = wbuf + (ko & 1) * 4096;
        // T14 async-STAGE: issue next slice loads early; write to LDS late
        uint4 nf0, nf1;
        if (ko < 26) {
            const uint4* g = (const uint4*)(w00 + (size_t)(ko + 1) * 4096);
            nf0 = g[tid]; nf1 = g[tid + 256];
        }
        int j0 = nbr_s[vl0 * 27 + ko];
        int j1 = nbr_s[vl1 * 27 + ko];
        bool m0 = j0 >= 0, m1 = j1 >= 0;
        const bf16x8* xr0 = (const bf16x8*)(xb + (size_t)(m0 ? j0 : 0) * 128 + q * 8);
        const bf16x8* xr1 = (const bf16x8*)(xb + (size_t)(m1 ? j1 : 0) * 128 + q * 8);
        bf16x8 a0[4], a1[4];
#pragma unroll
        for (int kc = 0; kc < 4; ++kc) {
            a0[kc] = m0 ? xr0[kc * 4] : zero;
            a1[kc] = m1 ? xr1[kc * 4] : zero;
        }
        const bf16x8* wp = (const bf16x8*)cur + lane;
        __builtin_amdgcn_s_setprio(1);
#pragma unroll
        for (int kc = 0; kc < 4; ++kc) {
            bf16x8 bb0 = wp[kc * 128];
            bf16x8 bb1 = wp[kc * 128 + 64];
            t00 = __builtin_amdgcn_mfma_f32_16x16x32_bf16(a0[kc], bb0, t00, 0, 0, 0);
            t01 = __builtin_amdgcn_mfma_f32_16x16x32_bf16(a0[kc], bb1, t01, 0, 0, 0);
            t10 = __builtin_amdgcn_mfma_f32_16x16x32_bf16(a1[kc], bb0, t10, 0, 0, 0);
            t11 = __builtin_amdgcn_mfma_f32_16x16x32_bf16(a1[kc], bb1, t11, 0, 0, 0);
        }
        __builtin_amdgcn_s_setprio(0);
        if (ko == 13) {                              // center offset == own row
            const bf16x8* wq = (const bf16x8*)(w10) + lane;
            __builtin_amdgcn_s_setprio(1);
#pragma unroll
            for (int kc = 0; kc < 4; ++kc) {
                bf16x8 c0 = wq[kc * 128];
                bf16x8 c1 = wq[kc * 128 + 64];
                u00 = __builtin_amdgcn_mfma_f32_16x16x32_bf16(a0[kc], c0, u00, 0, 0, 0);
                u01 = __builtin_amdgcn_mfma_f32_16x16x32_bf16(a0[kc], c1, u01, 0, 0, 0);
                u10 = __builtin_amdgcn_mfma_f32_16x16x32_bf16(a1[kc], c0, u10, 0, 0, 0);
                u11 = __builtin_amdgcn_mfma_f32_16x16x32_bf16(a1[kc], c1, u11, 0, 0, 0);
            }
            __builtin_amdgcn_s_setprio(0);
        }
        if (ko < 26) {   // land prefetched slice into the other buffer
            unsigned short* nxt = wbuf + ((ko + 1) & 1) * 4096;
            ((uint4*)nxt)[tid] = nf0;
            ((uint4*)nxt)[tid + 256] = nf1;
        }
        __syncthreads();   // rotate buffers; also protects nbr_s/wbuf lifetimes
    }

    // epilogue: bias + relu -> bf16 via LDS transpose, coalesced store
    // (loop ended with a barrier -> safe to overwrite the union region)
    int col = lane & 15;
    float bt0 = b00[col], bt1 = b00[16 + col];
    float bu0 = b10[col], bu1 = b10[16 + col];
#pragma unroll
    for (int r = 0; r < 4; ++r) {
        int row0 = wave * 32 + q * 4 + r;
        unsigned short* sp0 = stage + row0 * 72;
        sp0[col]      = f2bf(fmaxf(t00[r] + bt0, 0.f));
        sp0[16 + col] = f2bf(fmaxf(t01[r] + bt1, 0.f));
        sp0[32 + col] = f2bf(fmaxf(u00[r] + bu0, 0.f));
        sp0[48 + col] = f2bf(fmaxf(u01[r] + bu1, 0.f));
        unsigned short* sp1 = sp0 + 16 * 72;
        sp1[col]      = f2bf(fmaxf(t10[r] + bt0, 0.f));
        sp1[16 + col] = f2bf(fmaxf(t11[r] + bt1, 0.f));
        sp1[32 + col] = f2bf(fmaxf(u10[r] + bu0, 0.f));
        sp1[48 + col] = f2bf(fmaxf(u11[r] + bu1, 0.f));
    }
    __syncthreads();
    uint4* g4 = (uint4*)(s_out + (size_t)vb * 64);
    for (int i = tid; i < 1024; i += 256) {
        int row = i >> 3, c = i & 7;
        g4[row * 8 + c] = *(const uint4*)(stage + row * 72 + c * 8);
    }
}

// ---------------- kernel B: out = [conv01(t)+b01 | relu(conv11(u)+b11)@W12+b12] + x
// Same LDS weight-staging scheme: w01 (4 KB) + w11 (2 KB) per ko, double-
// buffered. LDS: nbr_s[13824] + wbufB[2][6144] = 26112 B; vstage unions at 0.
__global__ __launch_bounds__(256) void k_convB(
    const unsigned short* __restrict__ s_in,
    const float* __restrict__ x,
    const int* __restrict__ nbr_eff,
    const unsigned short* __restrict__ w01, const unsigned short* __restrict__ w11,
    const unsigned short* __restrict__ w12,
    const float* __restrict__ b01, const float* __restrict__ b11,
    const float* __restrict__ b12,
    float* __restrict__ out)
{
    __shared__ alignas(16) unsigned char shraw[26112];
    int*            nbr_s  = (int*)shraw;                         // [0,13824)
    unsigned short* wbufB  = (unsigned short*)(shraw + 13824);    // 2 x 3072 us
    unsigned short* vstage = (unsigned short*)shraw;              // post-loop union

    int tid = threadIdx.x;
    int lb = ((blockIdx.x & 7) << 8) | (blockIdx.x >> 3);
    int vb = lb * 128;
    {
        const i32x4* nsrc = (const i32x4*)(nbr_eff + (size_t)vb * 27);
        for (int i = tid; i < 864; i += 256)
            ((i32x4*)nbr_s)[i] = __builtin_nontemporal_load(nsrc + i);
    }
    {   // stage ko=0: w01 slice 4096 B (1 uint4/thread), w11 slice 2048 B (tid<128)
        uint4 p0 = ((const uint4*)w01)[tid];
        ((uint4*)wbufB)[tid] = p0;
        if (tid < 128) {
            uint4 p1 = ((const uint4*)w11)[tid];
            ((uint4*)(wbufB + 2048))[tid] = p1;
        }
    }
    __syncthreads();

    int lane = tid & 63, wave = tid >> 6;
    int m = lane & 15, q = lane >> 4;
    int vl0 = wave * 32 + m, vl1 = vl0 + 16;

    const bf16x8 zero = {0,0,0,0,0,0,0,0};
    f32x4 zz = {0.f,0.f,0.f,0.f};
    f32x4 o[2][4];
    f32x4 v[2][2];
#pragma unroll
    for (int tl = 0; tl < 2; ++tl) {
        o[tl][0] = zz; o[tl][1] = zz; o[tl][2] = zz; o[tl][3] = zz;
        v[tl][0] = zz; v[tl][1] = zz;
    }

#pragma unroll
    for (int ko = 0; ko < 27; ++ko) {
        const unsigned short* cur = wbufB + (ko & 1) * 3072;
        uint4 nf0, nf1;
        if (ko < 26) {
            nf0 = ((const uint4*)(w01 + (size_t)(ko + 1) * 2048))[tid];
            if (tid < 128)
                nf1 = ((const uint4*)(w11 + (size_t)(ko + 1) * 1024))[tid];
        }
        int j0 = nbr_s[vl0 * 27 + ko];
        int j1 = nbr_s[vl1 * 27 + ko];
        bool m0 = j0 >= 0, m1 = j1 >= 0;
        const bf16x8* sr0 = (const bf16x8*)(s_in + (size_t)(m0 ? j0 : 0) * 64 + q * 8);
        const bf16x8* sr1 = (const bf16x8*)(s_in + (size_t)(m1 ? j1 : 0) * 64 + q * 8);
        bf16x8 at0 = m0 ? sr0[0] : zero;
        bf16x8 au0 = m0 ? sr0[4] : zero;
        bf16x8 at1 = m1 ? sr1[0] : zero;
        bf16x8 au1 = m1 ? sr1[4] : zero;
        const bf16x8* wp1 = (const bf16x8*)cur + lane;
        const bf16x8* wp2 = (const bf16x8*)(cur + 2048) + lane;
        __builtin_amdgcn_s_setprio(1);
#pragma unroll
        for (int nt = 0; nt < 4; ++nt) {
            bf16x8 bb = wp1[nt * 64];
            o[0][nt] = __builtin_amdgcn_mfma_f32_16x16x32_bf16(at0, bb, o[0][nt], 0, 0, 0);
            o[1][nt] = __builtin_amdgcn_mfma_f32_16x16x32_bf16(at1, bb, o[1][nt], 0, 0, 0);
        }
#pragma unroll
        for (int nt = 0; nt < 2; ++nt) {
            bf16x8 bb = wp2[nt * 64];
            v[0][nt] = __builtin_amdgcn_mfma_f32_16x16x32_bf16(au0, bb, v[0][nt], 0, 0, 0);
            v[1][nt] = __builtin_amdgcn_mfma_f32_16x16x32_bf16(au1, bb, v[1][nt], 0, 0, 0);
        }
        __builtin_amdgcn_s_setprio(0);
        if (ko < 26) {
            unsigned short* nxt = wbufB + ((ko + 1) & 1) * 3072;
            ((uint4*)nxt)[tid] = nf0;
            if (tid < 128) ((uint4*)(nxt + 2048))[tid] = nf1;
        }
        __syncthreads();
    }

    // v = relu(v + b11): C-layout -> A-layout via wave-private LDS round-trip
    // (loop ended with a barrier -> union region free)
    int col = lane & 15;
    {
        float bv0 = b11[col], bv1 = b11[16 + col];
#pragma unroll
        for (int tl = 0; tl < 2; ++tl) {
            unsigned short* vs = vstage + (wave * 2 + tl) * 640;
#pragma unroll
            for (int r = 0; r < 4; ++r) {
                int row = q * 4 + r;
                vs[row * 40 + col]      = f2bf(fmaxf(v[tl][0][r] + bv0, 0.f));
                vs[row * 40 + 16 + col] = f2bf(fmaxf(v[tl][1][r] + bv1, 0.f));
            }
        }
    }
    const bf16x8* wp3 = (const bf16x8*)(w12) + lane;
    bf16x8 w3[4];
#pragma unroll
    for (int nt = 0; nt < 4; ++nt) w3[nt] = wp3[nt * 64];
    f32x4 p[2][4];
#pragma unroll
    for (int tl = 0; tl < 2; ++tl) {
        bf16x8 av = *(const bf16x8*)(vstage + (wave * 2 + tl) * 640 + m * 40 + q * 8);
#pragma unroll
        for (int nt = 0; nt < 4; ++nt)
            p[tl][nt] = __builtin_amdgcn_mfma_f32_16x16x32_bf16(av, w3[nt], zz, 0, 0, 0);
    }

    // direct C-layout stores: 16-lane 64B segments, residual add from x
    float bo[4], bp[4];
#pragma unroll
    for (int nt = 0; nt < 4; ++nt) { bo[nt] = b01[nt * 16 + col]; bp[nt] = b12[nt * 16 + col]; }
#pragma unroll
    for (int tl = 0; tl < 2; ++tl) {
#pragma unroll
        for (int r = 0; r < 4; ++r) {
            int row = vb + wave * 32 + tl * 16 + q * 4 + r;
            const float* xr = x + (size_t)row * 128;
            float* orow = out + (size_t)row * 128;
#pragma unroll
            for (int nt = 0; nt < 4; ++nt) {
                float x0 = __builtin_nontemporal_load(xr + nt * 16 + col);
                float x1 = __builtin_nontemporal_load(xr + 64 + nt * 16 + col);
                __builtin_nontemporal_store(o[tl][nt][r] + bo[nt] + x0,
                                            orow + nt * 16 + col);
                __builtin_nontemporal_store(p[tl][nt][r] + bp[nt] + x1,
                                            orow + 64 + nt * 16 + col);
            }
        }
    }
}

extern "C" void kernel_launch(void* const* d_in, const int* in_sizes, int n_in,
                              void* d_out, int out_size, void* d_ws, size_t ws_size,
                              hipStream_t stream) {
    const float* x   = (const float*)d_in[0];
    const int*   nbr = (const int*)d_in[1];
    const void*  mask = d_in[2];
    const float* W00 = (const float*)d_in[3];
    const float* b00 = (const float*)d_in[4];
    const float* W01 = (const float*)d_in[5];
    const float* b01 = (const float*)d_in[6];
    const float* W10 = (const float*)d_in[7];
    const float* b10 = (const float*)d_in[8];
    const float* W11 = (const float*)d_in[9];
    const float* b11 = (const float*)d_in[10];
    const float* W12 = (const float*)d_in[11];
    const float* b12 = (const float*)d_in[12];
    float* out = (float*)d_out;

    char* ws = (char*)d_ws;
    unsigned short* xb     = (unsigned short*)(ws);               // 64 MB
    unsigned short* s      = (unsigned short*)(ws + 67108864);    // 32 MB
    int*            nbr_eff= (int*)           (ws + 100663296);   // 27 MB
    unsigned short* w00p   = (unsigned short*)(ws + 128974848);   // 216 KB
    unsigned short* w10p   = (unsigned short*)(ws + 129196032);   // 8 KB
    unsigned short* w01p   = (unsigned short*)(ws + 129204224);   // 108 KB
    unsigned short* w11p   = (unsigned short*)(ws + 129314816);   // 54 KB
    unsigned short* w12p   = (unsigned short*)(ws + 129370112);   // 4 KB
    int*            flag   = (int*)           (ws + 129374208);

    k_detect<<<1, 64, 0, stream>>>((const int*)mask, flag);
    k_prep<<<PREP_GRID, 256, 0, stream>>>(nbr, mask, flag, nbr_eff, x, (u32x4*)xb,
                                          W00, W10, W01, W11, W12,
                                          w00p, w10p, w01p, w11p, w12p);
    k_convA<<<NVOX/128, 256, 0, stream>>>(xb, nbr_eff, w00p, w10p, b00, b10, s);
    k_convB<<<NVOX/128, 256, 0, stream>>>(s, x, nbr_eff, w01p, w11p, w12p,
                                          b01, b11, b12, out);
}